// Round 5
// baseline (686.835 us; speedup 1.0000x reference)
//
#include <hip/hip_runtime.h>

#define NIN    128
#define NOUT   512
#define NBATCH 16384
#define KF     8384            // native feature count
#define KP2    8832            // aligned-padded order: 16 linear groups + 1088 cross groups, x8
#define NG     (KP2 / 8)       // 1104 groups
#define NTK2   (KP2 / 64)      // 138 K-tiles (even)
#define XSP    136             // xS pitch (elems): 272 B, col 135 = ones
#define NTK    (KF / 64)       // 131 (fallback)
#define XP     136
#define AP     72

typedef float f32x4 __attribute__((ext_vector_type(4)));
typedef __bf16 bf16x8 __attribute__((ext_vector_type(8)));
typedef __bf16 bf16x4 __attribute__((ext_vector_type(4)));
typedef unsigned int u32x4 __attribute__((ext_vector_type(4)));

__device__ __forceinline__ int triS(int i) { return (i * (257 - i)) >> 1; }

// ================= K-order table (round-3 verified) =================
__global__ void k_tbl(unsigned int* __restrict__ tbl)
{
  int g = blockIdx.x * 256 + threadIdx.x;
  if (g >= NG) return;
  unsigned int e;
  if (g < 16) {
    e = 135u | ((unsigned)(g * 8) << 16);
  } else {
    int gp = g - 16;
    int b = 0;
    #pragma unroll
    for (int bb = 1; bb <= 15; ++bb) {
      int C = 8 * (16 * bb - bb * (bb - 1) / 2);
      if (gp >= C) b = bb;
    }
    int C   = 8 * (16 * b - b * (b - 1) / 2);
    int r   = gp - C;
    int per = 16 - b;
    int i   = 8 * b + r / per;
    int q   = r % per;
    e = (unsigned)i | ((unsigned)(8 * b + 8 * q) << 16);
  }
  tbl[g] = e;
}

// ================= Wt2[n][k'] = bf16(W[src(k')][n]); pads -> 0 (verified) =====
__global__ void k_wt2(const float* __restrict__ W,
                      const unsigned int* __restrict__ tbl,
                      __bf16* __restrict__ Wt)
{
  __shared__ __bf16 tile[64][65];
  const int kb   = blockIdx.x >> 3;
  const int nbw  = blockIdx.x & 7;
  const int lane = threadIdx.x & 63;
  const int grp  = threadIdx.x >> 6;
  #pragma unroll 4
  for (int it = 0; it < 16; ++it) {
    int kl = it * 4 + grp;
    int kp = kb * 64 + kl;
    unsigned int e = tbl[kp >> 3];
    int i = (int)(e & 0xFFFFu);
    int j = (int)(e >> 16) + (kp & 7);
    float v = 0.f;
    if (i == 135) {
      v = W[(size_t)kp * NOUT + nbw * 64 + lane];
    } else if (j >= i) {
      int src = 128 + i * 128 - i * (i - 1) / 2 + (j - i);
      v = W[(size_t)src * NOUT + nbw * 64 + lane];
    }
    tile[kl][lane] = (__bf16)v;
  }
  __syncthreads();
  #pragma unroll 4
  for (int it = 0; it < 16; ++it) {
    int nl = it * 4 + grp;
    Wt[(size_t)(nbw * 64 + nl) * KP2 + kb * 64 + lane] = tile[lane][nl];
  }
}

// ========== main GEMM: 128m x 128n block, grid 512 (2 blocks/CU, 8 waves/CU) ==
// 4 waves = (wm, wk): wave owns 64m x 128n over k-tiles kt === wk (mod 2).
// Bt[2] = one buffer per k-parity; 1 barrier per k-tile. A-frags in registers.
// Epilogue: wave pairs (wid ^ 2) combine partial sums through freed LDS.
__global__ __launch_bounds__(256, 2) void k_gemm4(
    const float* __restrict__ X,
    const __bf16* __restrict__ Wt,
    const float* __restrict__ bias,
    const unsigned int* __restrict__ tbl,
    float* __restrict__ out)
{
  __shared__ __align__(16) __bf16 xS[128 * XSP];   // 34816 B, col135 = 1.0
  __shared__ __align__(16) __bf16 Bt[2][128 * 64]; // 32768 B, chunk-XOR swizzled
  __shared__ unsigned short tbl_s[NG];             // 2208 B  (total 69792 B)

  const int tid  = threadIdx.x;
  const int lane = tid & 63;
  const int wid  = tid >> 6;
  const int wm   = wid & 1;           // m-half
  const int wk   = wid >> 1;          // k-parity
  const int mb   = blockIdx.x >> 2;
  const int nb   = blockIdx.x & 3;    // 8%4==0 -> each XCD sees one 2.26MB Wt slice

  for (int g = tid; g < NG; g += 256) {
    unsigned int e = tbl[g];
    tbl_s[g] = (unsigned short)((e & 0xFFu) | ((e >> 16) << 8));  // i | j0<<8
  }

  { // stage xS (row-major bf16) + ones column
    const float* xg = X + (size_t)mb * 128 * NIN;
    const int m = tid >> 1, h = tid & 1;
    #pragma unroll
    for (int it = 0; it < 16; ++it) {
      int c4 = h * 64 + it * 4;
      f32x4 v = *reinterpret_cast<const f32x4*>(xg + m * NIN + c4);
      bf16x4 b;
      #pragma unroll
      for (int e2 = 0; e2 < 4; ++e2) b[e2] = (__bf16)v[e2];
      *reinterpret_cast<bf16x4*>(&xS[m * XSP + c4]) = b;
    }
    if (tid < 128) xS[tid * XSP + 135] = (__bf16)1.0f;
  }

  // B staging: thread covers (n = sn + rep*32, chunk sc) for both tiles of a pair
  const int sn = tid >> 3;            // 0..31
  const int sc = tid & 7;             // chunk
  const __bf16* wrow = Wt + (size_t)(nb * 128 + sn) * KP2 + sc * 8;
  bf16x8 pf[8];                       // r = t*4 + rep  (t = tile parity)

  f32x4 acc[4][8];
  #pragma unroll
  for (int a = 0; a < 4; ++a)
    #pragma unroll
    for (int b = 0; b < 8; ++b)
      acc[a][b] = f32x4{0.f, 0.f, 0.f, 0.f};

  // prologue: load + write pair 0 (tiles 0,1)
  #pragma unroll
  for (int r = 0; r < 8; ++r) {
    int t = r >> 2, rep = r & 3;
    pf[r] = *reinterpret_cast<const bf16x8*>(wrow + (size_t)rep * 32 * KP2 + t * 64);
  }
  #pragma unroll
  for (int r = 0; r < 8; ++r) {
    int t = r >> 2, rep = r & 3;
    int n = sn + rep * 32;
    *reinterpret_cast<bf16x8*>(&Bt[t][n * 64 + ((sc ^ (n & 7)) * 8)]) = pf[r];
  }
  __syncthreads();

  const int NP = NTK2 / 2;            // 69 pairs
  for (int p = 0; p < NP; ++p) {
    const int kt = 2 * p + wk;        // this wave's tile
    if (p + 1 < NP) {                 // issue next pair's loads (hide under MFMA)
      #pragma unroll
      for (int r = 0; r < 8; ++r) {
        int t = r >> 2, rep = r & 3;
        pf[r] = *reinterpret_cast<const bf16x8*>(
            wrow + (size_t)rep * 32 * KP2 + (size_t)(2 * (p + 1) + t) * 64);
      }
    }

    #pragma unroll
    for (int kh = 0; kh < 2; ++kh) {
      // ---- A fragments in registers (bit-exact bf16 unpack + f32 mul) ----
      unsigned short e = tbl_s[kt * 8 + kh * 4 + (lane >> 4)];
      const int i  = (int)(e & 0xFFu);
      const int j0 = (int)(e >> 8);
      bf16x8 af[4];
      #pragma unroll
      for (int mi = 0; mi < 4; ++mi) {
        int m = wm * 64 + mi * 16 + (lane & 15);
        u32x4 va = *reinterpret_cast<const u32x4*>(&xS[m * XSP + j0]);
        unsigned short svu = *reinterpret_cast<const unsigned short*>(&xS[m * XSP + i]);
        float sv = __builtin_bit_cast(float, (unsigned int)svu << 16);
        bf16x8 a;
        #pragma unroll
        for (int q = 0; q < 4; ++q) {
          float lo = __builtin_bit_cast(float, va[q] << 16);
          float hi = __builtin_bit_cast(float, va[q] & 0xFFFF0000u);
          a[2 * q]     = (__bf16)(lo * sv);   // adjacent casts -> v_cvt_pk_bf16_f32
          a[2 * q + 1] = (__bf16)(hi * sv);
        }
        af[mi] = a;
      }
      // ---- B fragments + MFMA ----
      const int cb = kh * 4 + (lane >> 4);
      #pragma unroll
      for (int ni = 0; ni < 8; ++ni) {
        int n = ni * 16 + (lane & 15);
        bf16x8 bv = *reinterpret_cast<const bf16x8*>(
            &Bt[wk][n * 64 + ((cb ^ (n & 7)) * 8)]);
        #pragma unroll
        for (int mi = 0; mi < 4; ++mi)
          acc[mi][ni] = __builtin_amdgcn_mfma_f32_16x16x32_bf16(af[mi], bv, acc[mi][ni], 0, 0, 0);
      }
    }

    __syncthreads();                  // all waves done reading this pair
    if (p + 1 < NP) {
      #pragma unroll
      for (int r = 0; r < 8; ++r) {
        int t = r >> 2, rep = r & 3;
        int n = sn + rep * 32;
        *reinterpret_cast<bf16x8*>(&Bt[t][n * 64 + ((sc ^ (n & 7)) * 8)]) = pf[r];
      }
      __syncthreads();                // writes visible before next compute
    }
  }

  // ---- epilogue: combine k-parity partials via freed LDS (Bt + xS = 64KB) ----
  {
    // region(wid): waves 0,1 -> Bt (16KB each); waves 2,3 -> xS (16KB each)
    float* myreg = (wid < 2 ? reinterpret_cast<float*>(&Bt[0][0])
                            : reinterpret_cast<float*>(&xS[0])) + (wid & 1) * 4096;
    #pragma unroll
    for (int mi = 0; mi < 4; ++mi)
      #pragma unroll
      for (int nj = 0; nj < 4; ++nj) {
        int ni = (1 - wk) * 4 + nj;   // dump the half I do NOT write out
        *reinterpret_cast<f32x4*>(myreg + ((mi * 4 + nj) * 64 + lane) * 4) = acc[mi][ni];
      }
    __syncthreads();
    const int pw = wid ^ 2;           // partner: same wm, other wk
    const float* preg = (pw < 2 ? reinterpret_cast<const float*>(&Bt[0][0])
                                : reinterpret_cast<const float*>(&xS[0])) + (pw & 1) * 4096;
    #pragma unroll
    for (int nj = 0; nj < 4; ++nj) {
      int ni = wk * 4 + nj;           // my output half
      int n  = nb * 128 + ni * 16 + (lane & 15);
      float bv = bias[n];
      #pragma unroll
      for (int mi = 0; mi < 4; ++mi) {
        f32x4 o = *reinterpret_cast<const f32x4*>(preg + ((mi * 4 + nj) * 64 + lane) * 4);
        int mloc = wm * 64 + mi * 16 + ((lane >> 4) << 2);
        #pragma unroll
        for (int q = 0; q < 4; ++q) {
          size_t row = (size_t)mb * 128 + mloc + q;
          out[row * NOUT + n] = acc[mi][ni][q] + o[q] + bv;
        }
      }
    }
  }
}

// ================= fallback tiers (round-2/3 verified) =================
__global__ void k_wt(const float* __restrict__ W, __bf16* __restrict__ Wt)
{
  __shared__ __bf16 tile[64][65];
  const int kb   = blockIdx.x >> 3;
  const int nbw  = blockIdx.x & 7;
  const int lane = threadIdx.x & 63;
  const int grp  = threadIdx.x >> 6;
  #pragma unroll 4
  for (int it = 0; it < 16; ++it) {
    int kl = it * 4 + grp;
    tile[kl][lane] = (__bf16)W[(size_t)(kb * 64 + kl) * NOUT + nbw * 64 + lane];
  }
  __syncthreads();
  #pragma unroll 4
  for (int it = 0; it < 16; ++it) {
    int nl = it * 4 + grp;
    Wt[(size_t)(nbw * 64 + nl) * KF + kb * 64 + lane] = tile[lane][nl];
  }
}

template<bool WS>
__global__ __launch_bounds__(256, 2) void k_gemm(
    const float* __restrict__ X, const float* __restrict__ W,
    const __bf16* __restrict__ Wt, const float* __restrict__ bias,
    float* __restrict__ out)
{
  __shared__ __align__(16) __bf16 xT[128 * XP];
  __shared__ __align__(16) __bf16 At[128 * AP];
  __shared__ __align__(16) __bf16 Bt[128 * AP];
  const int tid = threadIdx.x, lane = tid & 63, wid = tid >> 6;
  const int mb = blockIdx.x >> 2, nb = blockIdx.x & 3;
  const int wr = wid >> 1, wc = wid & 1, kk = lane;
  {
    const float* xg = X + (size_t)mb * 128 * 128;
    #pragma unroll
    for (int it = 0; it < 16; ++it) {
      int row = it * 8 + (tid >> 5);
      int c4 = (tid & 31) * 4;
      f32x4 v = *reinterpret_cast<const f32x4*>(xg + row * 128 + c4);
      #pragma unroll
      for (int e = 0; e < 4; ++e) xT[(c4 + e) * XP + row] = (__bf16)v[e];
    }
  }
  f32x4 acc[4][4];
  #pragma unroll
  for (int a = 0; a < 4; ++a)
    #pragma unroll
    for (int b = 0; b < 4; ++b) acc[a][b] = f32x4{0.f, 0.f, 0.f, 0.f};
  __syncthreads();
  for (int kt = 0; kt < NTK; ++kt) {
    if (WS) {
      #pragma unroll
      for (int rep = 0; rep < 4; ++rep) {
        int id = rep * 256 + tid;
        int n = id >> 3, c = id & 7;
        bf16x8 v = *reinterpret_cast<const bf16x8*>(Wt + (size_t)(nb * 128 + n) * KF + kt * 64 + c * 8);
        *reinterpret_cast<bf16x8*>(&Bt[n * AP + c * 8]) = v;
      }
    } else {
      #pragma unroll
      for (int rep = 0; rep < 8; ++rep) {
        int r = rep * 8 + (tid >> 5);
        int cL = (tid & 31) * 4;
        f32x4 wv = *reinterpret_cast<const f32x4*>(W + (size_t)(kt * 64 + r) * NOUT + nb * 128 + cL);
        #pragma unroll
        for (int e = 0; e < 4; ++e) Bt[(cL + e) * AP + r] = (__bf16)wv[e];
      }
    }
    const int k = kt * 64 + kk;
    if (kt >= 2) {
      int idx = k - 128;
      int i = (int)((257.0f - sqrtf((float)(66049 - 8 * idx))) * 0.5f);
      if (i < 0) i = 0;
      if (i > 127) i = 127;
      while (i < 127 && triS(i + 1) <= idx) ++i;
      while (i > 0 && triS(i) > idx) --i;
      int j = i + (idx - triS(i));
      #pragma unroll
      for (int mg = 0; mg < 4; ++mg) {
        int m0 = wid * 32 + mg * 8;
        bf16x8 va = *reinterpret_cast<const bf16x8*>(&xT[i * XP + m0]);
        bf16x8 vb = *reinterpret_cast<const bf16x8*>(&xT[j * XP + m0]);
        #pragma unroll
        for (int q = 0; q < 8; ++q)
          At[(m0 + q) * AP + kk] = (__bf16)((float)va[q] * (float)vb[q]);
      }
    } else {
      #pragma unroll
      for (int mg = 0; mg < 4; ++mg) {
        int m0 = wid * 32 + mg * 8;
        bf16x8 va = *reinterpret_cast<const bf16x8*>(&xT[k * XP + m0]);
        #pragma unroll
        for (int q = 0; q < 8; ++q) At[(m0 + q) * AP + kk] = va[q];
      }
    }
    __syncthreads();
    #pragma unroll
    for (int kh = 0; kh < 2; ++kh) {
      const int koff = kh * 32 + 8 * (lane >> 4);
      bf16x8 af[4], bfv[4];
      #pragma unroll
      for (int mi = 0; mi < 4; ++mi) {
        int m = wr * 64 + mi * 16 + (lane & 15);
        af[mi] = *reinterpret_cast<const bf16x8*>(&At[m * AP + koff]);
      }
      #pragma unroll
      for (int ni = 0; ni < 4; ++ni) {
        int n = wc * 64 + ni * 16 + (lane & 15);
        bfv[ni] = *reinterpret_cast<const bf16x8*>(&Bt[n * AP + koff]);
      }
      #pragma unroll
      for (int mi = 0; mi < 4; ++mi)
        #pragma unroll
        for (int ni = 0; ni < 4; ++ni)
          acc[mi][ni] = __builtin_amdgcn_mfma_f32_16x16x32_bf16(af[mi], bfv[ni], acc[mi][ni], 0, 0, 0);
    }
    __syncthreads();
  }
  #pragma unroll
  for (int ni = 0; ni < 4; ++ni) {
    int n = nb * 128 + wc * 64 + ni * 16 + (lane & 15);
    float bv = bias[n];
    #pragma unroll
    for (int mi = 0; mi < 4; ++mi) {
      int mloc = wr * 64 + mi * 16 + ((lane >> 4) << 2);
      #pragma unroll
      for (int q = 0; q < 4; ++q) {
        size_t row = (size_t)mb * 128 + mloc + q;
        out[row * NOUT + n] = acc[mi][ni][q] + bv;
      }
    }
  }
}

extern "C" void kernel_launch(void* const* d_in, const int* in_sizes, int n_in,
                              void* d_out, int out_size, void* d_ws, size_t ws_size,
                              hipStream_t stream)
{
  const float* X    = (const float*)d_in[0];
  const float* W    = (const float*)d_in[1];
  const float* bias = (const float*)d_in[2];
  float* out        = (float*)d_out;

  const size_t wt2_bytes = (size_t)NOUT * KP2 * 2;            // 9,043,968
  const size_t need2     = wt2_bytes + (size_t)NG * 4;
  const size_t wt_bytes  = (size_t)NOUT * KF * 2;

  if (d_ws && ws_size >= need2) {
    __bf16* Wt        = (__bf16*)d_ws;
    unsigned int* tbl = (unsigned int*)((char*)d_ws + wt2_bytes);
    k_tbl<<<dim3((NG + 255) / 256), dim3(256), 0, stream>>>(tbl);
    k_wt2<<<dim3(NTK2 * 8), dim3(256), 0, stream>>>(W, tbl, Wt);
    k_gemm4<<<dim3((NBATCH / 128) * 4), dim3(256), 0, stream>>>(X, Wt, bias, tbl, out);
  } else if (d_ws && ws_size >= wt_bytes) {
    __bf16* Wt = (__bf16*)d_ws;
    k_wt<<<dim3(NTK * 8), dim3(256), 0, stream>>>(W, Wt);
    k_gemm<true><<<dim3((NBATCH / 128) * 4), dim3(256), 0, stream>>>(X, W, Wt, bias, out);
  } else {
    k_gemm<false><<<dim3((NBATCH / 128) * 4), dim3(256), 0, stream>>>(X, W, nullptr, bias, out);
  }
}

// Round 6
// 173.509 us; speedup vs baseline: 3.9585x; 3.9585x over previous
//
#include <hip/hip_runtime.h>

#define NIN    128
#define NOUT   512
#define NBATCH 16384
#define KF     8384            // native feature count
#define KP2    8832            // aligned-padded order: 16 linear groups + 1088 cross groups, x8
#define NG     (KP2 / 8)       // 1104 groups
#define NTK2   (KP2 / 64)      // 138 K-tiles (even)
#define XSP    136             // xS pitch (elems): 272 B, col 135 = ones
#define NTK    (KF / 64)       // 131 (fallback)
#define XP     136
#define AP     72

typedef float f32x4 __attribute__((ext_vector_type(4)));
typedef __bf16 bf16x8 __attribute__((ext_vector_type(8)));
typedef __bf16 bf16x4 __attribute__((ext_vector_type(4)));
typedef unsigned int u32x4 __attribute__((ext_vector_type(4)));

__device__ __forceinline__ int triS(int i) { return (i * (257 - i)) >> 1; }

// ================= K-order table (round-3 verified) =================
__global__ void k_tbl(unsigned int* __restrict__ tbl)
{
  int g = blockIdx.x * 256 + threadIdx.x;
  if (g >= NG) return;
  unsigned int e;
  if (g < 16) {
    e = 135u | ((unsigned)(g * 8) << 16);
  } else {
    int gp = g - 16;
    int b = 0;
    #pragma unroll
    for (int bb = 1; bb <= 15; ++bb) {
      int C = 8 * (16 * bb - bb * (bb - 1) / 2);
      if (gp >= C) b = bb;
    }
    int C   = 8 * (16 * b - b * (b - 1) / 2);
    int r   = gp - C;
    int per = 16 - b;
    int i   = 8 * b + r / per;
    int q   = r % per;
    e = (unsigned)i | ((unsigned)(8 * b + 8 * q) << 16);
  }
  tbl[g] = e;
}

// ================= Wt2[n][k'] = bf16(W[src(k')][n]); pads -> 0 (verified) =====
__global__ void k_wt2(const float* __restrict__ W,
                      const unsigned int* __restrict__ tbl,
                      __bf16* __restrict__ Wt)
{
  __shared__ __bf16 tile[64][65];
  const int kb   = blockIdx.x >> 3;
  const int nbw  = blockIdx.x & 7;
  const int lane = threadIdx.x & 63;
  const int grp  = threadIdx.x >> 6;
  #pragma unroll 4
  for (int it = 0; it < 16; ++it) {
    int kl = it * 4 + grp;
    int kp = kb * 64 + kl;
    unsigned int e = tbl[kp >> 3];
    int i = (int)(e & 0xFFFFu);
    int j = (int)(e >> 16) + (kp & 7);
    float v = 0.f;
    if (i == 135) {
      v = W[(size_t)kp * NOUT + nbw * 64 + lane];
    } else if (j >= i) {
      int src = 128 + i * 128 - i * (i - 1) / 2 + (j - i);
      v = W[(size_t)src * NOUT + nbw * 64 + lane];
    }
    tile[kl][lane] = (__bf16)v;
  }
  __syncthreads();
  #pragma unroll 4
  for (int it = 0; it < 16; ++it) {
    int nl = it * 4 + grp;
    Wt[(size_t)(nbw * 64 + nl) * KP2 + kb * 64 + lane] = tile[lane][nl];
  }
}

// ========== main GEMM: 128m x 128n block, grid 512 (2 blocks/CU, 8 waves/CU) ==
// 4 waves = (wm, wk): wave owns 64m x 128n over k-tiles kt === wk (mod 2).
// Bt[2] = one buffer per k-parity; 1 barrier per k-tile. A-frags in registers.
// Epilogue: wave pairs (wid ^ 2) combine partials via freed LDS — ALL acc
// indices compile-time (rule #20: runtime index would demote acc to scratch).
__global__ __launch_bounds__(256, 2) void k_gemm4(
    const float* __restrict__ X,
    const __bf16* __restrict__ Wt,
    const float* __restrict__ bias,
    const unsigned int* __restrict__ tbl,
    float* __restrict__ out)
{
  __shared__ __align__(16) __bf16 xS[128 * XSP];   // 34816 B, col135 = 1.0
  __shared__ __align__(16) __bf16 Bt[2][128 * 64]; // 32768 B, chunk-XOR swizzled
  __shared__ unsigned short tbl_s[NG];             // 2208 B  (total 69792 B)

  const int tid  = threadIdx.x;
  const int lane = tid & 63;
  const int wid  = tid >> 6;
  const int wm   = wid & 1;           // m-half
  const int wk   = wid >> 1;          // k-parity
  const int mb   = blockIdx.x >> 2;
  const int nb   = blockIdx.x & 3;    // 8%4==0 -> each XCD sees one 2.26MB Wt slice

  for (int g = tid; g < NG; g += 256) {
    unsigned int e = tbl[g];
    tbl_s[g] = (unsigned short)((e & 0xFFu) | ((e >> 16) << 8));  // i | j0<<8
  }

  { // stage xS (row-major bf16) + ones column
    const float* xg = X + (size_t)mb * 128 * NIN;
    const int m = tid >> 1, h = tid & 1;
    #pragma unroll
    for (int it = 0; it < 16; ++it) {
      int c4 = h * 64 + it * 4;
      f32x4 v = *reinterpret_cast<const f32x4*>(xg + m * NIN + c4);
      bf16x4 b;
      #pragma unroll
      for (int e2 = 0; e2 < 4; ++e2) b[e2] = (__bf16)v[e2];
      *reinterpret_cast<bf16x4*>(&xS[m * XSP + c4]) = b;
    }
    if (tid < 128) xS[tid * XSP + 135] = (__bf16)1.0f;
  }

  // B staging: thread covers (n = sn + rep*32, chunk sc) for both tiles of a pair
  const int sn = tid >> 3;            // 0..31
  const int sc = tid & 7;             // chunk
  const __bf16* wrow = Wt + (size_t)(nb * 128 + sn) * KP2 + sc * 8;
  bf16x8 pf[8];                       // r = t*4 + rep  (t = tile parity)

  f32x4 acc[4][8];
  #pragma unroll
  for (int a = 0; a < 4; ++a)
    #pragma unroll
    for (int b = 0; b < 8; ++b)
      acc[a][b] = f32x4{0.f, 0.f, 0.f, 0.f};

  // prologue: load + write pair 0 (tiles 0,1)
  #pragma unroll
  for (int r = 0; r < 8; ++r) {
    int t = r >> 2, rep = r & 3;
    pf[r] = *reinterpret_cast<const bf16x8*>(wrow + (size_t)rep * 32 * KP2 + t * 64);
  }
  #pragma unroll
  for (int r = 0; r < 8; ++r) {
    int t = r >> 2, rep = r & 3;
    int n = sn + rep * 32;
    *reinterpret_cast<bf16x8*>(&Bt[t][n * 64 + ((sc ^ (n & 7)) * 8)]) = pf[r];
  }
  __syncthreads();

  const int NP = NTK2 / 2;            // 69 pairs
  for (int p = 0; p < NP; ++p) {
    const int kt = 2 * p + wk;        // this wave's tile
    if (p + 1 < NP) {                 // issue next pair's loads (hide under MFMA)
      #pragma unroll
      for (int r = 0; r < 8; ++r) {
        int t = r >> 2, rep = r & 3;
        pf[r] = *reinterpret_cast<const bf16x8*>(
            wrow + (size_t)rep * 32 * KP2 + (size_t)(2 * (p + 1) + t) * 64);
      }
    }

    #pragma unroll
    for (int kh = 0; kh < 2; ++kh) {
      // ---- A fragments in registers (bit-exact bf16 unpack + f32 mul) ----
      unsigned short e = tbl_s[kt * 8 + kh * 4 + (lane >> 4)];
      const int i  = (int)(e & 0xFFu);
      const int j0 = (int)(e >> 8);
      bf16x8 af[4];
      #pragma unroll
      for (int mi = 0; mi < 4; ++mi) {
        int m = wm * 64 + mi * 16 + (lane & 15);
        u32x4 va = *reinterpret_cast<const u32x4*>(&xS[m * XSP + j0]);
        unsigned short svu = *reinterpret_cast<const unsigned short*>(&xS[m * XSP + i]);
        float sv = __builtin_bit_cast(float, (unsigned int)svu << 16);
        bf16x8 a;
        #pragma unroll
        for (int q = 0; q < 4; ++q) {
          float lo = __builtin_bit_cast(float, va[q] << 16);
          float hi = __builtin_bit_cast(float, va[q] & 0xFFFF0000u);
          a[2 * q]     = (__bf16)(lo * sv);   // adjacent casts -> v_cvt_pk_bf16_f32
          a[2 * q + 1] = (__bf16)(hi * sv);
        }
        af[mi] = a;
      }
      // ---- B fragments + MFMA ----
      const int cb = kh * 4 + (lane >> 4);
      #pragma unroll
      for (int ni = 0; ni < 8; ++ni) {
        int n = ni * 16 + (lane & 15);
        bf16x8 bv = *reinterpret_cast<const bf16x8*>(
            &Bt[wk][n * 64 + ((cb ^ (n & 7)) * 8)]);
        #pragma unroll
        for (int mi = 0; mi < 4; ++mi)
          acc[mi][ni] = __builtin_amdgcn_mfma_f32_16x16x32_bf16(af[mi], bv, acc[mi][ni], 0, 0, 0);
      }
    }

    __syncthreads();                  // all waves done reading this pair
    if (p + 1 < NP) {
      #pragma unroll
      for (int r = 0; r < 8; ++r) {
        int t = r >> 2, rep = r & 3;
        int n = sn + rep * 32;
        *reinterpret_cast<bf16x8*>(&Bt[t][n * 64 + ((sc ^ (n & 7)) * 8)]) = pf[r];
      }
      __syncthreads();                // writes visible before next compute
    }
  }

  // ---- epilogue: combine k-parity partials via freed LDS (Bt + xS = 64KB) ----
  // wave (wm,wk) dumps the acc half it does NOT output; partner (wid^2) has the
  // other k-parity. All acc indices are literals inside the wk branches.
  {
    float* myreg = (wid < 2 ? reinterpret_cast<float*>(&Bt[0][0])
                            : reinterpret_cast<float*>(&xS[0])) + (wid & 1) * 4096;
    if (wk == 0) {
      #pragma unroll
      for (int mi = 0; mi < 4; ++mi)
        #pragma unroll
        for (int nj = 0; nj < 4; ++nj)
          *reinterpret_cast<f32x4*>(myreg + ((mi * 4 + nj) * 64 + lane) * 4) = acc[mi][4 + nj];
    } else {
      #pragma unroll
      for (int mi = 0; mi < 4; ++mi)
        #pragma unroll
        for (int nj = 0; nj < 4; ++nj)
          *reinterpret_cast<f32x4*>(myreg + ((mi * 4 + nj) * 64 + lane) * 4) = acc[mi][nj];
    }
    __syncthreads();
    const int pw = wid ^ 2;           // partner: same wm, other wk
    const float* preg = (pw < 2 ? reinterpret_cast<const float*>(&Bt[0][0])
                                : reinterpret_cast<const float*>(&xS[0])) + (pw & 1) * 4096;
    if (wk == 0) {
      #pragma unroll
      for (int nj = 0; nj < 4; ++nj) {
        int n = nb * 128 + nj * 16 + (lane & 15);
        float bv = bias[n];
        #pragma unroll
        for (int mi = 0; mi < 4; ++mi) {
          f32x4 o = *reinterpret_cast<const f32x4*>(preg + ((mi * 4 + nj) * 64 + lane) * 4);
          int mloc = wm * 64 + mi * 16 + ((lane >> 4) << 2);
          #pragma unroll
          for (int q = 0; q < 4; ++q) {
            size_t row = (size_t)mb * 128 + mloc + q;
            out[row * NOUT + n] = acc[mi][nj][q] + o[q] + bv;
          }
        }
      }
    } else {
      #pragma unroll
      for (int nj = 0; nj < 4; ++nj) {
        int n = nb * 128 + (4 + nj) * 16 + (lane & 15);
        float bv = bias[n];
        #pragma unroll
        for (int mi = 0; mi < 4; ++mi) {
          f32x4 o = *reinterpret_cast<const f32x4*>(preg + ((mi * 4 + nj) * 64 + lane) * 4);
          int mloc = wm * 64 + mi * 16 + ((lane >> 4) << 2);
          #pragma unroll
          for (int q = 0; q < 4; ++q) {
            size_t row = (size_t)mb * 128 + mloc + q;
            out[row * NOUT + n] = acc[mi][4 + nj][q] + o[q] + bv;
          }
        }
      }
    }
  }
}

// ================= fallback tiers (round-2/3 verified) =================
__global__ void k_wt(const float* __restrict__ W, __bf16* __restrict__ Wt)
{
  __shared__ __bf16 tile[64][65];
  const int kb   = blockIdx.x >> 3;
  const int nbw  = blockIdx.x & 7;
  const int lane = threadIdx.x & 63;
  const int grp  = threadIdx.x >> 6;
  #pragma unroll 4
  for (int it = 0; it < 16; ++it) {
    int kl = it * 4 + grp;
    tile[kl][lane] = (__bf16)W[(size_t)(kb * 64 + kl) * NOUT + nbw * 64 + lane];
  }
  __syncthreads();
  #pragma unroll 4
  for (int it = 0; it < 16; ++it) {
    int nl = it * 4 + grp;
    Wt[(size_t)(nbw * 64 + nl) * KF + kb * 64 + lane] = tile[lane][nl];
  }
}

template<bool WS>
__global__ __launch_bounds__(256, 2) void k_gemm(
    const float* __restrict__ X, const float* __restrict__ W,
    const __bf16* __restrict__ Wt, const float* __restrict__ bias,
    float* __restrict__ out)
{
  __shared__ __align__(16) __bf16 xT[128 * XP];
  __shared__ __align__(16) __bf16 At[128 * AP];
  __shared__ __align__(16) __bf16 Bt[128 * AP];
  const int tid = threadIdx.x, lane = tid & 63, wid = tid >> 6;
  const int mb = blockIdx.x >> 2, nb = blockIdx.x & 3;
  const int wr = wid >> 1, wc = wid & 1, kk = lane;
  {
    const float* xg = X + (size_t)mb * 128 * 128;
    #pragma unroll
    for (int it = 0; it < 16; ++it) {
      int row = it * 8 + (tid >> 5);
      int c4 = (tid & 31) * 4;
      f32x4 v = *reinterpret_cast<const f32x4*>(xg + row * 128 + c4);
      #pragma unroll
      for (int e = 0; e < 4; ++e) xT[(c4 + e) * XP + row] = (__bf16)v[e];
    }
  }
  f32x4 acc[4][4];
  #pragma unroll
  for (int a = 0; a < 4; ++a)
    #pragma unroll
    for (int b = 0; b < 4; ++b) acc[a][b] = f32x4{0.f, 0.f, 0.f, 0.f};
  __syncthreads();
  for (int kt = 0; kt < NTK; ++kt) {
    if (WS) {
      #pragma unroll
      for (int rep = 0; rep < 4; ++rep) {
        int id = rep * 256 + tid;
        int n = id >> 3, c = id & 7;
        bf16x8 v = *reinterpret_cast<const bf16x8*>(Wt + (size_t)(nb * 128 + n) * KF + kt * 64 + c * 8);
        *reinterpret_cast<bf16x8*>(&Bt[n * AP + c * 8]) = v;
      }
    } else {
      #pragma unroll
      for (int rep = 0; rep < 8; ++rep) {
        int r = rep * 8 + (tid >> 5);
        int cL = (tid & 31) * 4;
        f32x4 wv = *reinterpret_cast<const f32x4*>(W + (size_t)(kt * 64 + r) * NOUT + nb * 128 + cL);
        #pragma unroll
        for (int e = 0; e < 4; ++e) Bt[(cL + e) * AP + r] = (__bf16)wv[e];
      }
    }
    const int k = kt * 64 + kk;
    if (kt >= 2) {
      int idx = k - 128;
      int i = (int)((257.0f - sqrtf((float)(66049 - 8 * idx))) * 0.5f);
      if (i < 0) i = 0;
      if (i > 127) i = 127;
      while (i < 127 && triS(i + 1) <= idx) ++i;
      while (i > 0 && triS(i) > idx) --i;
      int j = i + (idx - triS(i));
      #pragma unroll
      for (int mg = 0; mg < 4; ++mg) {
        int m0 = wid * 32 + mg * 8;
        bf16x8 va = *reinterpret_cast<const bf16x8*>(&xT[i * XP + m0]);
        bf16x8 vb = *reinterpret_cast<const bf16x8*>(&xT[j * XP + m0]);
        #pragma unroll
        for (int q = 0; q < 8; ++q)
          At[(m0 + q) * AP + kk] = (__bf16)((float)va[q] * (float)vb[q]);
      }
    } else {
      #pragma unroll
      for (int mg = 0; mg < 4; ++mg) {
        int m0 = wid * 32 + mg * 8;
        bf16x8 va = *reinterpret_cast<const bf16x8*>(&xT[k * XP + m0]);
        #pragma unroll
        for (int q = 0; q < 8; ++q) At[(m0 + q) * AP + kk] = va[q];
      }
    }
    __syncthreads();
    #pragma unroll
    for (int kh = 0; kh < 2; ++kh) {
      const int koff = kh * 32 + 8 * (lane >> 4);
      bf16x8 af[4], bfv[4];
      #pragma unroll
      for (int mi = 0; mi < 4; ++mi) {
        int m = wr * 64 + mi * 16 + (lane & 15);
        af[mi] = *reinterpret_cast<const bf16x8*>(&At[m * AP + koff]);
      }
      #pragma unroll
      for (int ni = 0; ni < 4; ++ni) {
        int n = wc * 64 + ni * 16 + (lane & 15);
        bfv[ni] = *reinterpret_cast<const bf16x8*>(&Bt[n * AP + koff]);
      }
      #pragma unroll
      for (int mi = 0; mi < 4; ++mi)
        #pragma unroll
        for (int ni = 0; ni < 4; ++ni)
          acc[mi][ni] = __builtin_amdgcn_mfma_f32_16x16x32_bf16(af[mi], bfv[ni], acc[mi][ni], 0, 0, 0);
    }
    __syncthreads();
  }
  #pragma unroll
  for (int ni = 0; ni < 4; ++ni) {
    int n = nb * 128 + wc * 64 + ni * 16 + (lane & 15);
    float bv = bias[n];
    #pragma unroll
    for (int mi = 0; mi < 4; ++mi) {
      int mloc = wr * 64 + mi * 16 + ((lane >> 4) << 2);
      #pragma unroll
      for (int q = 0; q < 4; ++q) {
        size_t row = (size_t)mb * 128 + mloc + q;
        out[row * NOUT + n] = acc[mi][ni][q] + bv;
      }
    }
  }
}

extern "C" void kernel_launch(void* const* d_in, const int* in_sizes, int n_in,
                              void* d_out, int out_size, void* d_ws, size_t ws_size,
                              hipStream_t stream)
{
  const float* X    = (const float*)d_in[0];
  const float* W    = (const float*)d_in[1];
  const float* bias = (const float*)d_in[2];
  float* out        = (float*)d_out;

  const size_t wt2_bytes = (size_t)NOUT * KP2 * 2;            // 9,043,968
  const size_t need2     = wt2_bytes + (size_t)NG * 4;
  const size_t wt_bytes  = (size_t)NOUT * KF * 2;

  if (d_ws && ws_size >= need2) {
    __bf16* Wt        = (__bf16*)d_ws;
    unsigned int* tbl = (unsigned int*)((char*)d_ws + wt2_bytes);
    k_tbl<<<dim3((NG + 255) / 256), dim3(256), 0, stream>>>(tbl);
    k_wt2<<<dim3(NTK2 * 8), dim3(256), 0, stream>>>(W, tbl, Wt);
    k_gemm4<<<dim3((NBATCH / 128) * 4), dim3(256), 0, stream>>>(X, Wt, bias, tbl, out);
  } else if (d_ws && ws_size >= wt_bytes) {
    __bf16* Wt = (__bf16*)d_ws;
    k_wt<<<dim3(NTK * 8), dim3(256), 0, stream>>>(W, Wt);
    k_gemm<true><<<dim3((NBATCH / 128) * 4), dim3(256), 0, stream>>>(X, W, Wt, bias, out);
  } else {
    k_gemm<false><<<dim3((NBATCH / 128) * 4), dim3(256), 0, stream>>>(X, W, nullptr, bias, out);
  }
}